// Round 1
// baseline (264.106 us; speedup 1.0000x reference)
//
#include <hip/hip_runtime.h>
#include <hip/hip_bf16.h>

#define BATCH   65536
#define FEAT    128
#define KDIM    256

typedef __attribute__((ext_vector_type(8))) short bf16x8;
typedef __attribute__((ext_vector_type(4))) float f32x4;

__device__ __forceinline__ short f2bf(float f) {
    return __builtin_bit_cast(short, __float2bfloat16(f));
}

__device__ __forceinline__ bf16x8 cvt8(f32x4 lo, f32x4 hi) {
    bf16x8 r;
    r[0] = f2bf(lo[0]); r[1] = f2bf(lo[1]); r[2] = f2bf(lo[2]); r[3] = f2bf(lo[3]);
    r[4] = f2bf(hi[0]); r[5] = f2bf(hi[1]); r[6] = f2bf(hi[2]); r[7] = f2bf(hi[3]);
    return r;
}

__device__ __forceinline__ float sigmoidf_(float x) {
    return 1.0f / (1.0f + __expf(-x));
}
__device__ __forceinline__ float tanhf_(float x) {
    float xc = fminf(fmaxf(x, -15.0f), 15.0f);
    float e = __expf(-2.0f * xc);
    return (1.0f - e) / (1.0f + e);
}

// One wave owns: 32 batch rows (2 m-blocks of 16) x 16 hidden-cols (cg) for ALL
// four gates. W fragments (4 gates x 8 k-steps) live in VGPRs for the whole
// kernel. No LDS, no barriers; waves fully independent.
__global__ __launch_bounds__(256, 2)
void lstm_fused(const float* __restrict__ inp, const float* __restrict__ hid,
                const float* __restrict__ cel,
                const float* __restrict__ Wf, const float* __restrict__ bf_,
                const float* __restrict__ Wi, const float* __restrict__ bi_,
                const float* __restrict__ Wo, const float* __restrict__ bo_,
                const float* __restrict__ Wc, const float* __restrict__ bc_,
                float* __restrict__ out)
{
    const int tid  = threadIdx.x;
    const int lane = tid & 63;
    const int wid  = tid >> 6;     // 0..3
    const int b    = blockIdx.x;   // 0..511
    // XCD-aware mapping: blocks b and b+8 (same XCD under %8 round-robin)
    // form the cg{0-3}/cg{4-7} pair for the same row-tile base -> A-tile L2 reuse.
    const int u      = b >> 3;                  // 0..63
    const int xcd    = b & 7;
    const int rtBase = xcd * 32 + (u >> 1);     // 0..255
    const int cg     = ((u & 1) << 2) | wid;    // 0..7

    const int lr = lane & 15;   // A-row / W-row within 16; also output col offset
    const int lk = lane >> 4;   // k-group 0..3
    const int j  = cg * 16 + lr;   // hidden-unit column 0..127

    // ---- preload W fragments into registers (fp32 -> bf16), 128 VGPR ----
    bf16x8 w[4][8];
    {
        const float* wsrc[4] = {Wf, Wi, Wo, Wc};
        #pragma unroll
        for (int g = 0; g < 4; ++g) {
            const float* src = wsrc[g] + (size_t)j * KDIM + lk * 8;
            #pragma unroll
            for (int ks = 0; ks < 8; ++ks) {
                f32x4 lo = *(const f32x4*)(src + ks * 32);
                f32x4 hi = *(const f32x4*)(src + ks * 32 + 4);
                w[g][ks] = cvt8(lo, hi);
            }
        }
    }
    const float bsf = bf_[j], bsi = bi_[j], bso = bo_[j], bsc = bc_[j];

    float* outH = out;
    float* outC = out + (size_t)BATCH * FEAT;

    for (int it = 0; it < 8; ++it) {
        const int R0 = (rtBase + it * 256) * 32;

        const float* aInp = inp + (size_t)(R0 + lr) * FEAT + lk * 8;
        const float* aHid = hid + (size_t)(R0 + lr) * FEAT + lk * 8;

        // preload cell values for the epilogue (completes under the GEMM)
        float cv[8];
        #pragma unroll
        for (int mb = 0; mb < 2; ++mb)
            #pragma unroll
            for (int t = 0; t < 4; ++t)
                cv[mb * 4 + t] = cel[(size_t)(R0 + mb * 16 + lk * 4 + t) * FEAT + j];

        // accumulators init with bias (MFMA C-in)
        f32x4 acc[2][4];
        #pragma unroll
        for (int mb = 0; mb < 2; ++mb)
            #pragma unroll
            for (int t = 0; t < 4; ++t) {
                acc[mb][0][t] = bsf; acc[mb][1][t] = bsi;
                acc[mb][2][t] = bso; acc[mb][3][t] = bsc;
            }

        // depth-1 prefetched K-loop: frag(ks, mb): row = R0+mb*16+lr, k = ks*32+lk*8
        f32x4 plo[2][2], phi[2][2];
        #pragma unroll
        for (int mb = 0; mb < 2; ++mb) {
            plo[0][mb] = *(const f32x4*)(aInp + mb * 16 * FEAT);
            phi[0][mb] = *(const f32x4*)(aInp + mb * 16 * FEAT + 4);
        }

        #pragma unroll
        for (int ks = 0; ks < 8; ++ks) {
            const int cur = ks & 1, nxt = cur ^ 1;
            if (ks < 7) {
                const float* nb2 = ((ks + 1) < 4 ? aInp : aHid) + ((ks + 1) & 3) * 32;
                #pragma unroll
                for (int mb = 0; mb < 2; ++mb) {
                    plo[nxt][mb] = *(const f32x4*)(nb2 + mb * 16 * FEAT);
                    phi[nxt][mb] = *(const f32x4*)(nb2 + mb * 16 * FEAT + 4);
                }
            }
            bf16x8 a0 = cvt8(plo[cur][0], phi[cur][0]);
            bf16x8 a1 = cvt8(plo[cur][1], phi[cur][1]);
            #pragma unroll
            for (int g = 0; g < 4; ++g) {
                acc[0][g] = __builtin_amdgcn_mfma_f32_16x16x32_bf16(a0, w[g][ks], acc[0][g], 0, 0, 0);
                acc[1][g] = __builtin_amdgcn_mfma_f32_16x16x32_bf16(a1, w[g][ks], acc[1][g], 0, 0, 0);
            }
        }

        // lane-local LSTM epilogue: gates for (row R, col j) all live in this lane
        #pragma unroll
        for (int mb = 0; mb < 2; ++mb) {
            #pragma unroll
            for (int t = 0; t < 4; ++t) {
                const int R = R0 + mb * 16 + lk * 4 + t;
                float fg = sigmoidf_(acc[mb][0][t]);
                float ig = sigmoidf_(acc[mb][1][t]);
                float og = sigmoidf_(acc[mb][2][t]);
                float gg = tanhf_(acc[mb][3][t]);
                float nc = fg * cv[mb * 4 + t] + ig * gg;
                float nh = og * tanhf_(nc);
                outH[(size_t)R * FEAT + j] = nh;
                outC[(size_t)R * FEAT + j] = nc;
            }
        }
    }
}

extern "C" void kernel_launch(void* const* d_in, const int* in_sizes, int n_in,
                              void* d_out, int out_size, void* d_ws, size_t ws_size,
                              hipStream_t stream) {
    const float* inp = (const float*)d_in[0];
    const float* hid = (const float*)d_in[1];
    const float* cel = (const float*)d_in[2];
    const float* Wf  = (const float*)d_in[3];
    const float* bf  = (const float*)d_in[4];
    const float* Wi  = (const float*)d_in[5];
    const float* bi  = (const float*)d_in[6];
    const float* Wo  = (const float*)d_in[7];
    const float* bo  = (const float*)d_in[8];
    const float* Wc  = (const float*)d_in[9];
    const float* bc  = (const float*)d_in[10];
    float* out = (float*)d_out;

    lstm_fused<<<dim3(512), dim3(256), 0, stream>>>(
        inp, hid, cel, Wf, bf, Wi, bi, Wo, bo, Wc, bc, out);
}

// Round 3
// 213.461 us; speedup vs baseline: 1.2373x; 1.2373x over previous
//
#include <hip/hip_runtime.h>
#include <hip/hip_bf16.h>

#define BATCH   65536
#define FEAT    128
#define KDIM    256

typedef __attribute__((ext_vector_type(8))) short bf16x8;
typedef __attribute__((ext_vector_type(4))) float f32x4;

__device__ __forceinline__ short f2bf(float f) {
    return __builtin_bit_cast(short, __float2bfloat16(f));
}

__device__ __forceinline__ bf16x8 cvt8(f32x4 lo, f32x4 hi) {
    bf16x8 r;
    r[0] = f2bf(lo[0]); r[1] = f2bf(lo[1]); r[2] = f2bf(lo[2]); r[3] = f2bf(lo[3]);
    r[4] = f2bf(hi[0]); r[5] = f2bf(hi[1]); r[6] = f2bf(hi[2]); r[7] = f2bf(hi[3]);
    return r;
}

__device__ __forceinline__ float sigmoidf_(float x) {
    return 1.0f / (1.0f + __expf(-x));
}
__device__ __forceinline__ float tanhf_(float x) {
    float xc = fminf(fmaxf(x, -15.0f), 15.0f);
    float e = __expf(-2.0f * xc);
    return (1.0f - e) / (1.0f + e);
}

// Block = 4 waves, persistent (grid 1024 = 4 blocks/CU exactly resident).
// Block tile per iteration: 32 batch rows x 16 hidden-cols (one cg) x 4 gates.
// Wave `wid` computes the partial gates over K-quarter [64*wid, 64*wid+64):
//   W regs per wave = 4 gates x 2 k-steps x bf16x8 = 32 VGPRs (vs 128 before,
//   which spilled). Partials reduced across waves via padded LDS, lane-local
//   LSTM epilogue. Target: <=128 unified regs -> 4 waves/SIMD.
__global__ __launch_bounds__(256, 4)
void lstm_ksplit(const float* __restrict__ inp, const float* __restrict__ hid,
                 const float* __restrict__ cel,
                 const float* __restrict__ Wf, const float* __restrict__ bfp,
                 const float* __restrict__ Wi, const float* __restrict__ bip,
                 const float* __restrict__ Wo, const float* __restrict__ bop,
                 const float* __restrict__ Wc, const float* __restrict__ bcp,
                 float* __restrict__ out)
{
    // pad 35: write banks = 3*lane%32 (bijective, 2-way over 64 lanes = free);
    // read banks ~2-way. 35840 B -> 4 blocks/CU fit in 160 KiB.
    __shared__ float lds[4][64][35];

    const int tid  = threadIdx.x;
    const int lane = tid & 63;
    const int wid  = tid >> 6;          // = kq, this wave's K-quarter
    const int bid  = blockIdx.x;
    const int cg   = bid >> 7;          // 0..7  column group
    const int rtg  = bid & 127;         // 0..127 row-tile group
    // XCD note: blocks {cg*128 + rtg} for fixed rtg all have bid%8 == rtg%8
    // -> the 8 blocks sharing a row-tile land on the same XCD's L2.

    const int lr = lane & 15;           // MFMA row/col-within-16
    const int lk = lane >> 4;           // k-subgroup 0..3
    const int j  = cg * 16 + lr;        // hidden-unit column 0..127

    const int kq = wid;
    const int k0 = (kq & 1) * 64;                  // offset inside inp/hid half
    const float* Asrc = (kq < 2) ? inp : hid;

    // ---- W fragments for this K-quarter: 32 VGPRs ----
    bf16x8 w[4][2];
    {
        const float* wsrc[4] = {Wf, Wi, Wo, Wc};
        #pragma unroll
        for (int g = 0; g < 4; ++g) {
            const float* s = wsrc[g] + (size_t)j * KDIM + kq * 64 + lk * 8;
            #pragma unroll
            for (int ks = 0; ks < 2; ++ks) {
                f32x4 lo = *(const f32x4*)(s + ks * 32);
                f32x4 hi = *(const f32x4*)(s + ks * 32 + 4);
                w[g][ks] = cvt8(lo, hi);
            }
        }
    }
    // bias for this lane's epilogue column (lane&15 == lr)
    const float bsf = bfp[j], bsi = bip[j], bso = bop[j], bsc = bcp[j];

    float* outH = out;
    float* outC = out + (size_t)BATCH * FEAT;

    for (int it = 0; it < 16; ++it) {
        const int R0 = (rtg + it * 128) * 32;

        // ---- A fragments: 8 dwordx4 issued together (MLP=8) ----
        const float* a = Asrc + (size_t)(R0 + lr) * FEAT + k0 + lk * 8;
        f32x4 alo[2][2], ahi[2][2];     // [ks][mb]
        #pragma unroll
        for (int ks = 0; ks < 2; ++ks)
            #pragma unroll
            for (int mb = 0; mb < 2; ++mb) {
                alo[ks][mb] = *(const f32x4*)(a + mb * 16 * FEAT + ks * 32);
                ahi[ks][mb] = *(const f32x4*)(a + mb * 16 * FEAT + ks * 32 + 4);
            }

        f32x4 acc[2][4];
        #pragma unroll
        for (int mb = 0; mb < 2; ++mb)
            #pragma unroll
            for (int g = 0; g < 4; ++g)
                acc[mb][g] = (f32x4){0.f, 0.f, 0.f, 0.f};

        #pragma unroll
        for (int ks = 0; ks < 2; ++ks) {
            bf16x8 a0 = cvt8(alo[ks][0], ahi[ks][0]);
            bf16x8 a1 = cvt8(alo[ks][1], ahi[ks][1]);
            #pragma unroll
            for (int g = 0; g < 4; ++g) {
                acc[0][g] = __builtin_amdgcn_mfma_f32_16x16x32_bf16(a0, w[g][ks], acc[0][g], 0, 0, 0);
                acc[1][g] = __builtin_amdgcn_mfma_f32_16x16x32_bf16(a1, w[g][ks], acc[1][g], 0, 0, 0);
            }
        }

        // ---- write this wave's partials ----
        #pragma unroll
        for (int mb = 0; mb < 2; ++mb)
            #pragma unroll
            for (int g = 0; g < 4; ++g)
                #pragma unroll
                for (int t = 0; t < 4; ++t)
                    lds[kq][lane][mb * 16 + g * 4 + t] = acc[mb][g][t];
        __syncthreads();

        // ---- cross-wave reduce + LSTM epilogue; wave wid owns 8 rows ----
        #pragma unroll
        for (int p = 0; p < 2; ++p) {
            const int rl  = wid * 8 + p * 4 + (lane >> 4);   // 0..31
            const int jc  = lane & 15;
            const int mb  = rl >> 4;
            const int lk2 = (rl >> 2) & 3;
            const int t   = rl & 3;
            const int sl  = lk2 * 16 + jc;   // source lane that produced (rl, jc)

            float s0 = 0.f, s1 = 0.f, s2 = 0.f, s3 = 0.f;
            #pragma unroll
            for (int q = 0; q < 4; ++q) {
                s0 += lds[q][sl][mb * 16 + 0 * 4 + t];
                s1 += lds[q][sl][mb * 16 + 1 * 4 + t];
                s2 += lds[q][sl][mb * 16 + 2 * 4 + t];
                s3 += lds[q][sl][mb * 16 + 3 * 4 + t];
            }

            const int R = R0 + rl;
            const size_t off = (size_t)R * FEAT + cg * 16 + jc;
            float cv = cel[off];
            float fg = sigmoidf_(s0 + bsf);
            float ig = sigmoidf_(s1 + bsi);
            float og = sigmoidf_(s2 + bso);
            float gg = tanhf_(s3 + bsc);
            float nc = fg * cv + ig * gg;
            float nh = og * tanhf_(nc);
            outH[off] = nh;
            outC[off] = nc;
        }
        __syncthreads();
    }
}

extern "C" void kernel_launch(void* const* d_in, const int* in_sizes, int n_in,
                              void* d_out, int out_size, void* d_ws, size_t ws_size,
                              hipStream_t stream) {
    const float* inp = (const float*)d_in[0];
    const float* hid = (const float*)d_in[1];
    const float* cel = (const float*)d_in[2];
    const float* Wf  = (const float*)d_in[3];
    const float* bf  = (const float*)d_in[4];
    const float* Wi  = (const float*)d_in[5];
    const float* bi  = (const float*)d_in[6];
    const float* Wo  = (const float*)d_in[7];
    const float* bo  = (const float*)d_in[8];
    const float* Wc  = (const float*)d_in[9];
    const float* bc  = (const float*)d_in[10];
    float* out = (float*)d_out;

    lstm_ksplit<<<dim3(1024), dim3(256), 0, stream>>>(
        inp, hid, cel, Wf, bf, Wi, bi, Wo, bo, Wc, bc, out);
}